// Round 10
// baseline (77.221 us; speedup 1.0000x reference)
//
#include <hip/hip_runtime.h>

#define H_TOKN 57
#define OUT_HW 800
#define NMASK 64
#define C_IN 768
#define C8N 96
#define L_OUT 21
#define NPIX 3249          // 57*57
#define M_TOT 6498         // 2*3249
#define YSTR 24            // y57 global channel stride (pixel-major)
#define TPLANE 3264        // y57T per-channel plane stride (3249 padded to /16)
#define SCALE (57.0f/800.0f)

// fused conv
#define BM 32
#define ESTR 40            // bf16 LDS row stride
#define HSTR 97            // f32 LDS row stride

// binsum (MFMA one-hot segment sum)
#define TILE_H 25
#define TILE_W 100
#define ROWS_T 4
#define COLS_T 10
#define NTAPS 40           // ROWS_T*COLS_T
#define YTSTR 28           // tap row stride: full 8 bank-groups for b128
#define IPAD 264
#define ZPAD 264
#define ZROWS 32
#define NSLICE 256
#define PSTR 28

// final (channel-major)
#define FR 16              // rows per stripe
#define RCL 60             // rowCl row stride (f32)

static __device__ __forceinline__ unsigned short f2bf(float f) {
  unsigned u = __float_as_uint(f);
  u += 0x7FFFu + ((u >> 16) & 1u);   // RTNE
  return (unsigned short)(u >> 16);
}

// ---------- Kernel A (fused): conv1(MFMA bf16) + relu + conv2; writes y57 AND y57T ----------
__global__ __launch_bounds__(256) void fused_conv_kernel(
    const float* __restrict__ e, const float* __restrict__ w1,
    const float* __restrict__ b1, const float* __restrict__ w2,
    float* __restrict__ y57, float* __restrict__ y57T)
{
  using bf16x8 = __attribute__((ext_vector_type(8))) short;
  using f32x4  = __attribute__((ext_vector_type(4))) float;
  __shared__ __align__(16) unsigned short eA[BM * ESTR];
  __shared__ __align__(16) unsigned short wB[C8N * ESTR];
  __shared__ __align__(16) float h_lds[BM * HSTR];
  __shared__ float w2_lds[L_OUT * C8N];
  __shared__ float b1_lds[C8N];

  const int tid = threadIdx.x;
  const int m0 = blockIdx.x * BM;
  const int lane = tid & 63;
  const int wv = tid >> 6;
  const int l15 = lane & 15;
  const int khi = (lane >> 4) << 3;
  const int wm = wv & 1;
  const int wn = wv >> 1;

  for (int i = tid; i < L_OUT * C8N; i += 256) w2_lds[i] = w2[i];
  if (tid < C8N) b1_lds[tid] = b1[tid];

  f32x4 acc[3];
  #pragma unroll
  for (int t = 0; t < 3; ++t) acc[t] = (f32x4){0.f, 0.f, 0.f, 0.f};

  for (int k0 = 0; k0 < C_IN; k0 += 32) {
    __syncthreads();
    {
      int r = tid >> 3, c4 = (tid & 7) << 2;
      int p = m0 + r; if (p >= M_TOT) p = M_TOT - 1;
      float4 v = *(const float4*)(e + (size_t)p * C_IN + k0 + c4);
      ushort4 s; s.x = f2bf(v.x); s.y = f2bf(v.y); s.z = f2bf(v.z); s.w = f2bf(v.w);
      *(ushort4*)&eA[r * ESTR + c4] = s;
    }
    #pragma unroll
    for (int q = 0; q < 3; ++q) {
      int f = tid + q * 256;
      int r = f >> 3, c4 = (f & 7) << 2;
      float4 v = *(const float4*)(w1 + (size_t)r * C_IN + k0 + c4);
      ushort4 s; s.x = f2bf(v.x); s.y = f2bf(v.y); s.z = f2bf(v.z); s.w = f2bf(v.w);
      *(ushort4*)&wB[r * ESTR + c4] = s;
    }
    __syncthreads();
    bf16x8 a = *(bf16x8*)&eA[(wm * 16 + l15) * ESTR + khi];
    #pragma unroll
    for (int tt = 0; tt < 3; ++tt) {
      bf16x8 b = *(bf16x8*)&wB[((wn * 3 + tt) * 16 + l15) * ESTR + khi];
      acc[tt] = __builtin_amdgcn_mfma_f32_16x16x32_bf16(a, b, acc[tt], 0, 0, 0);
    }
  }
  __syncthreads();
  #pragma unroll
  for (int tt = 0; tt < 3; ++tt) {
    int n = (wn * 3 + tt) * 16 + l15;
    float bv = b1_lds[n];
    #pragma unroll
    for (int r = 0; r < 4; ++r) {
      int pl = wm * 16 + ((lane >> 4) << 2) + r;
      h_lds[pl * HSTR + n] = fmaxf(acc[tt][r] + bv, 0.f);
    }
  }
  __syncthreads();
  for (int i = tid; i < BM * 24; i += 256) {
    int px = i & (BM - 1), l = i >> 5;
    float s = 0.f;
    if (l < L_OUT) {
      const float* hr = &h_lds[px * HSTR];
      const float* wr = &w2_lds[l * C8N];
      #pragma unroll 8
      for (int c = 0; c < C8N; ++c) s += hr[c] * wr[c];
    }
    int p = m0 + px;
    if (p < M_TOT) {
      y57[(size_t)p * YSTR + l] = s;
      if (l < L_OUT) {
        int bb = (p >= NPIX);
        int pp = p - bb * NPIX;
        y57T[((size_t)bb * 24 + l) * TPLANE + pp] = s;
      }
    }
  }
}

// ---------- Kernel B: MFMA one-hot segment sum (NO atomics) ----------
__global__ __launch_bounds__(256) void binsum_kernel(
    const int* __restrict__ labels, const float* __restrict__ y57,
    float* __restrict__ part)
{
  using bf16x8 = __attribute__((ext_vector_type(8))) short;
  using f32x4  = __attribute__((ext_vector_type(4))) float;
  __shared__ __align__(16) unsigned short It[NMASK * IPAD];
  __shared__ __align__(16) unsigned short zT[ZROWS * ZPAD];
  __shared__ __align__(16) float ytile[NTAPS * YTSTR];
  const int tid = threadIdx.x;
  const int lane = tid & 63, wv = tid >> 6;
  const int l15 = lane & 15, khi = (lane >> 4) << 3;
  const int wc0 = blockIdx.x * TILE_W;
  const int hr0 = blockIdx.y * TILE_H;
  const int b = blockIdx.z;

  for (int i = tid; i < NMASK * IPAD / 2; i += 256) ((unsigned*)It)[i] = 0u;
  for (int i = tid; i < ZROWS * ZPAD / 2; i += 256) ((unsigned*)zT)[i] = 0u;

  float thb = fminf(fmaxf((hr0 + 0.5f) * SCALE - 0.5f, 0.f), 56.f);
  const int ib = min((int)thb, 55);
  float twb = fminf(fmaxf((wc0 + 0.5f) * SCALE - 0.5f, 0.f), 56.f);
  const int jb = min((int)twb, 55);

  const float* yb = y57 + (size_t)b * NPIX * YSTR;
  for (int i = tid; i < NTAPS * 6; i += 256) {
    int t = i / 6, q = (i - t * 6) * 4;
    int r = t / COLS_T, cc = t - r * COLS_T;
    int I = min(ib + r, 56), J = min(jb + cc, 56);
    *(float4*)&ytile[t * YTSTR + q] =
        *(const float4*)(yb + ((size_t)I * H_TOKN + J) * YSTR + q);
  }

  const bool valid = tid < 250;
  const int dh = tid / 10;
  const int dwb = (tid - dh * 10) * 10;
  const int hh = hr0 + dh;
  float th = fminf(fmaxf((hh + 0.5f) * SCALE - 0.5f, 0.f), 56.f);
  int i0 = min((int)th, 55);
  const float fh = th - (float)i0;
  const int ri = i0 - ib;
  const int* lrow = labels + ((size_t)b * OUT_HW + hh) * OUT_HW;

  f32x4 acc0 = {0.f,0.f,0.f,0.f}, acc1 = {0.f,0.f,0.f,0.f};
  int prevm = 0;
  const unsigned short one = 0x3F80;

  __syncthreads();
  if (valid) zT[24 * ZPAD + tid] = one;

  for (int c = 0; c < 10; ++c) {
    if (valid) {
      int ww = wc0 + dwb + c;
      float tw = fminf(fmaxf((ww + 0.5f) * SCALE - 0.5f, 0.f), 56.f);
      int j0 = min((int)tw, 55);
      float fw = tw - (float)j0;
      int rj = j0 - jb;
      const float* t00 = &ytile[(ri * COLS_T + rj) * YTSTR];
      const float* t10 = t00 + COLS_T * YTSTR;
      float w11 = fh * fw, w10 = fh - w11, w01 = fw - w11;
      float w00 = 1.f - fh - fw + w11;
      int m = lrow[ww] & (NMASK - 1);
      #pragma unroll
      for (int q = 0; q < 6; ++q) {
        float4 A = *(const float4*)(t00 + 4 * q);
        float4 B = *(const float4*)(t00 + YTSTR + 4 * q);
        float4 C = *(const float4*)(t10 + 4 * q);
        float4 D = *(const float4*)(t10 + YTSTR + 4 * q);
        zT[(4*q+0) * ZPAD + tid] = f2bf(w00*A.x + w01*B.x + w10*C.x + w11*D.x);
        zT[(4*q+1) * ZPAD + tid] = f2bf(w00*A.y + w01*B.y + w10*C.y + w11*D.y);
        zT[(4*q+2) * ZPAD + tid] = f2bf(w00*A.z + w01*B.z + w10*C.z + w11*D.z);
        zT[(4*q+3) * ZPAD + tid] = f2bf(w00*A.w + w01*B.w + w10*C.w + w11*D.w);
      }
      It[prevm * IPAD + tid] = 0;
      It[m * IPAD + tid] = one;
      prevm = m;
    }
    __syncthreads();
    #pragma unroll
    for (int ks = 0; ks < 8; ++ks) {
      bf16x8 a  = *(bf16x8*)&It[(wv * 16 + l15) * IPAD + ks * 32 + khi];
      bf16x8 b0 = *(bf16x8*)&zT[l15 * ZPAD + ks * 32 + khi];
      bf16x8 b1 = *(bf16x8*)&zT[(16 + l15) * ZPAD + ks * 32 + khi];
      acc0 = __builtin_amdgcn_mfma_f32_16x16x32_bf16(a, b0, acc0, 0, 0, 0);
      acc1 = __builtin_amdgcn_mfma_f32_16x16x32_bf16(a, b1, acc1, 0, 0, 0);
    }
    __syncthreads();
  }

  float* pb = part + ((size_t)b * NSLICE +
                      (size_t)(blockIdx.y * gridDim.x + blockIdx.x)) * (NMASK * PSTR);
  const int g4 = (lane >> 4) << 2;
  #pragma unroll
  for (int r = 0; r < 4; ++r) {
    int m = wv * 16 + g4 + r;
    pb[m * PSTR + l15] = acc0[r];
    if (l15 <= 8) pb[m * PSTR + 16 + l15] = acc1[r];
  }
}

// ---------- Kernel B2: meanFgT[b][l][m] = sum(part)/cnt + b2 ----------
__global__ __launch_bounds__(256) void reduce_kernel(
    const float* __restrict__ part, const float* __restrict__ b2,
    float* __restrict__ meanFgT)
{
  const int bm = blockIdx.x;          // b*64 + m
  const int b = bm >> 6, m = bm & 63;
  const int tid = threadIdx.x;        // = slice
  const float* p = part + ((size_t)b * NSLICE + tid) * (NMASK * PSTR) + (size_t)m * PSTR;
  float4 v[7];
  #pragma unroll
  for (int q = 0; q < 7; ++q) v[q] = *(const float4*)(p + q * 4);
  #pragma unroll
  for (int off = 32; off > 0; off >>= 1) {
    #pragma unroll
    for (int q = 0; q < 7; ++q) {
      v[q].x += __shfl_down(v[q].x, off, 64);
      v[q].y += __shfl_down(v[q].y, off, 64);
      v[q].z += __shfl_down(v[q].z, off, 64);
      v[q].w += __shfl_down(v[q].w, off, 64);
    }
  }
  __shared__ float s_red[4][28];
  const int wid = tid >> 6, lane = tid & 63;
  if (lane == 0) {
    #pragma unroll
    for (int q = 0; q < 7; ++q) *(float4*)&s_red[wid][q * 4] = v[q];
  }
  __syncthreads();
  if (tid < L_OUT) {
    float cnt = s_red[0][24] + s_red[1][24] + s_red[2][24] + s_red[3][24];
    float t = s_red[0][tid] + s_red[1][tid] + s_red[2][tid] + s_red[3][tid];
    meanFgT[((size_t)b * L_OUT + tid) * NMASK + m] = t / fmaxf(cnt, 1.f) + b2[tid];
  }
}

// ---------- Kernel C (channel-major): out[b][l][stripe] ----------
// Block (l, stripe of 16 rows, b): stage lerped rows for channel l + per-w
// (fw,j0) table + per-channel means; write one contiguous 51KB region.
__global__ __launch_bounds__(256) void final_kernel(
    const float* __restrict__ y57T, const int* __restrict__ labels,
    const float* __restrict__ meanFgT, float* __restrict__ out)
{
  __shared__ __align__(16) float rowCl[FR * RCL];
  __shared__ __align__(16) float2 fwj[OUT_HW];
  __shared__ float meanFl[NMASK];
  const int tid = threadIdx.x;
  const int l = blockIdx.x;
  const int h0 = blockIdx.y * FR;
  const int b = blockIdx.z;

  // per-w interpolation table
  for (int w = tid; w < OUT_HW; w += 256) {
    float tw = fminf(fmaxf((w + 0.5f) * SCALE - 0.5f, 0.f), 56.f);
    int j0 = min((int)tw, 55);
    fwj[w] = make_float2(tw - (float)j0, __int_as_float(j0));
  }
  // per-channel means
  if (tid < NMASK) meanFl[tid] = meanFgT[((size_t)b * L_OUT + l) * NMASK + tid];
  // lerped rows for this channel
  const float* yTl = y57T + ((size_t)b * 24 + l) * TPLANE;
  for (int i = tid; i < FR * H_TOKN; i += 256) {
    int r = i / H_TOKN, j = i - r * H_TOKN;
    float th = fminf(fmaxf((h0 + r + 0.5f) * SCALE - 0.5f, 0.f), 56.f);
    int i0 = min((int)th, 55);
    float fh = th - (float)i0;
    float a = yTl[i0 * H_TOKN + j];
    float c = yTl[(i0 + 1) * H_TOKN + j];
    rowCl[r * RCL + j] = a + fh * (c - a);
  }
  __syncthreads();

  float* ob = out + (((size_t)b * L_OUT + l) * OUT_HW + h0) * OUT_HW;
  const int* lb = labels + ((size_t)b * OUT_HW + h0) * OUT_HW;
  for (int g = tid; g < FR * 200; g += 256) {
    int r = g / 200;
    int c4 = (g - r * 200) * 4;
    int4 la = *(const int4*)(lb + (size_t)r * OUT_HW + c4);
    const float* rc = &rowCl[r * RCL];
    float4 V;
    {
      float2 fj = fwj[c4 + 0];
      const float* s = rc + __float_as_int(fj.y);
      V.x = s[0] + fj.x * (s[1] - s[0]) + meanFl[la.x & 63];
    }
    {
      float2 fj = fwj[c4 + 1];
      const float* s = rc + __float_as_int(fj.y);
      V.y = s[0] + fj.x * (s[1] - s[0]) + meanFl[la.y & 63];
    }
    {
      float2 fj = fwj[c4 + 2];
      const float* s = rc + __float_as_int(fj.y);
      V.z = s[0] + fj.x * (s[1] - s[0]) + meanFl[la.z & 63];
    }
    {
      float2 fj = fwj[c4 + 3];
      const float* s = rc + __float_as_int(fj.y);
      V.w = s[0] + fj.x * (s[1] - s[0]) + meanFl[la.w & 63];
    }
    *(float4*)(ob + (size_t)r * OUT_HW + c4) = V;
  }
}

extern "C" void kernel_launch(void* const* d_in, const int* in_sizes, int n_in,
                              void* d_out, int out_size, void* d_ws, size_t ws_size,
                              hipStream_t stream)
{
  const float* e   = (const float*)d_in[0];
  const int*   lab = (const int*)d_in[1];
  const float* w1  = (const float*)d_in[2];
  const float* b1  = (const float*)d_in[3];
  const float* w2  = (const float*)d_in[4];
  const float* b2  = (const float*)d_in[5];
  float* out = (float*)d_out;
  float* ws  = (float*)d_ws;

  float* y57_ws  = ws;                                      // 6498*24 f32
  float* y57T_ws = y57_ws + (size_t)M_TOT * YSTR;           // 2*24*3264 f32
  float* part    = y57T_ws + (size_t)2 * 24 * TPLANE;       // 2*256*64*28 f32
  float* meanFgT = part + (size_t)2 * NSLICE * NMASK * PSTR; // 2*21*64 f32

  fused_conv_kernel<<<dim3((M_TOT + BM - 1) / BM), 256, 0, stream>>>(
      e, w1, b1, w2, y57_ws, y57T_ws);
  binsum_kernel<<<dim3(OUT_HW / TILE_W, OUT_HW / TILE_H, 2), 256, 0, stream>>>(
      lab, y57_ws, part);
  reduce_kernel<<<dim3(2 * NMASK), 256, 0, stream>>>(part, b2, meanFgT);
  final_kernel<<<dim3(L_OUT, OUT_HW / FR, 2), 256, 0, stream>>>(
      y57T_ws, lab, meanFgT, out);
}

// Round 11
// 71.117 us; speedup vs baseline: 1.0858x; 1.0858x over previous
//
#include <hip/hip_runtime.h>

#define H_TOKN 57
#define OUT_HW 800
#define NMASK 64
#define C_IN 768
#define C8N 96
#define L_OUT 21
#define NPIX 3249          // 57*57
#define M_TOT 6498         // 2*3249
#define YSTR 24            // y57 global channel stride
#define SCALE (57.0f/800.0f)

// fused conv
#define BM 32
#define ESTR 40            // bf16 LDS row stride
#define HSTR 97            // f32 LDS row stride

// binsum (MFMA one-hot segment sum)
#define TILE_H 25
#define TILE_W 100
#define ROWS_T 4
#define COLS_T 10
#define NTAPS 40           // ROWS_T*COLS_T
#define YTSTR 28           // tap row stride
#define IPAD 264
#define ZPAD 264
#define ZROWS 32
#define NSLICE 256
#define PSTR 28

// final
#define RCSTR 28
#define MFSTR 28
#define FROWS 8            // 100 y-blocks x 2 = 200 blocks: single round on 256 CUs

static __device__ __forceinline__ unsigned short f2bf(float f) {
  unsigned u = __float_as_uint(f);
  u += 0x7FFFu + ((u >> 16) & 1u);   // RTNE
  return (unsigned short)(u >> 16);
}

// ---------- Kernel A (fused): conv1(MFMA bf16) + relu + conv2 -> y57 ----------
__global__ __launch_bounds__(256) void fused_conv_kernel(
    const float* __restrict__ e, const float* __restrict__ w1,
    const float* __restrict__ b1, const float* __restrict__ w2,
    float* __restrict__ y57)
{
  using bf16x8 = __attribute__((ext_vector_type(8))) short;
  using f32x4  = __attribute__((ext_vector_type(4))) float;
  __shared__ __align__(16) unsigned short eA[BM * ESTR];
  __shared__ __align__(16) unsigned short wB[C8N * ESTR];
  __shared__ __align__(16) float h_lds[BM * HSTR];
  __shared__ float w2_lds[L_OUT * C8N];
  __shared__ float b1_lds[C8N];

  const int tid = threadIdx.x;
  const int m0 = blockIdx.x * BM;
  const int lane = tid & 63;
  const int wv = tid >> 6;
  const int l15 = lane & 15;
  const int khi = (lane >> 4) << 3;
  const int wm = wv & 1;
  const int wn = wv >> 1;

  for (int i = tid; i < L_OUT * C8N; i += 256) w2_lds[i] = w2[i];
  if (tid < C8N) b1_lds[tid] = b1[tid];

  f32x4 acc[3];
  #pragma unroll
  for (int t = 0; t < 3; ++t) acc[t] = (f32x4){0.f, 0.f, 0.f, 0.f};

  for (int k0 = 0; k0 < C_IN; k0 += 32) {
    __syncthreads();
    {
      int r = tid >> 3, c4 = (tid & 7) << 2;
      int p = m0 + r; if (p >= M_TOT) p = M_TOT - 1;
      float4 v = *(const float4*)(e + (size_t)p * C_IN + k0 + c4);
      ushort4 s; s.x = f2bf(v.x); s.y = f2bf(v.y); s.z = f2bf(v.z); s.w = f2bf(v.w);
      *(ushort4*)&eA[r * ESTR + c4] = s;
    }
    #pragma unroll
    for (int q = 0; q < 3; ++q) {
      int f = tid + q * 256;
      int r = f >> 3, c4 = (f & 7) << 2;
      float4 v = *(const float4*)(w1 + (size_t)r * C_IN + k0 + c4);
      ushort4 s; s.x = f2bf(v.x); s.y = f2bf(v.y); s.z = f2bf(v.z); s.w = f2bf(v.w);
      *(ushort4*)&wB[r * ESTR + c4] = s;
    }
    __syncthreads();
    bf16x8 a = *(bf16x8*)&eA[(wm * 16 + l15) * ESTR + khi];
    #pragma unroll
    for (int tt = 0; tt < 3; ++tt) {
      bf16x8 b = *(bf16x8*)&wB[((wn * 3 + tt) * 16 + l15) * ESTR + khi];
      acc[tt] = __builtin_amdgcn_mfma_f32_16x16x32_bf16(a, b, acc[tt], 0, 0, 0);
    }
  }
  __syncthreads();
  #pragma unroll
  for (int tt = 0; tt < 3; ++tt) {
    int n = (wn * 3 + tt) * 16 + l15;
    float bv = b1_lds[n];
    #pragma unroll
    for (int r = 0; r < 4; ++r) {
      int pl = wm * 16 + ((lane >> 4) << 2) + r;
      h_lds[pl * HSTR + n] = fmaxf(acc[tt][r] + bv, 0.f);
    }
  }
  __syncthreads();
  for (int i = tid; i < BM * 24; i += 256) {
    int px = i & (BM - 1), l = i >> 5;
    float s = 0.f;
    if (l < L_OUT) {
      const float* hr = &h_lds[px * HSTR];
      const float* wr = &w2_lds[l * C8N];
      #pragma unroll 8
      for (int c = 0; c < C8N; ++c) s += hr[c] * wr[c];
    }
    int p = m0 + px;
    if (p < M_TOT) y57[(size_t)p * YSTR + l] = s;
  }
}

// ---------- Kernel B: MFMA one-hot segment sum, register tap-caching ----------
__global__ __launch_bounds__(256) void binsum_kernel(
    const int* __restrict__ labels, const float* __restrict__ y57,
    float* __restrict__ part)
{
  using bf16x8 = __attribute__((ext_vector_type(8))) short;
  using f32x4  = __attribute__((ext_vector_type(4))) float;
  __shared__ __align__(16) unsigned short It[NMASK * IPAD];
  __shared__ __align__(16) unsigned short zT[ZROWS * ZPAD];
  __shared__ __align__(16) float ytile[NTAPS * YTSTR];
  const int tid = threadIdx.x;
  const int lane = tid & 63, wv = tid >> 6;
  const int l15 = lane & 15, khi = (lane >> 4) << 3;
  const int wc0 = blockIdx.x * TILE_W;
  const int hr0 = blockIdx.y * TILE_H;
  const int b = blockIdx.z;

  for (int i = tid; i < NMASK * IPAD / 2; i += 256) ((unsigned*)It)[i] = 0u;
  for (int i = tid; i < ZROWS * ZPAD / 2; i += 256) ((unsigned*)zT)[i] = 0u;

  float thb = fminf(fmaxf((hr0 + 0.5f) * SCALE - 0.5f, 0.f), 56.f);
  const int ib = min((int)thb, 55);
  float twb = fminf(fmaxf((wc0 + 0.5f) * SCALE - 0.5f, 0.f), 56.f);
  const int jb = min((int)twb, 55);

  const float* yb = y57 + (size_t)b * NPIX * YSTR;
  for (int i = tid; i < NTAPS * 6; i += 256) {
    int t = i / 6, q = (i - t * 6) * 4;
    int r = t / COLS_T, cc = t - r * COLS_T;
    int I = min(ib + r, 56), J = min(jb + cc, 56);
    *(float4*)&ytile[t * YTSTR + q] =
        *(const float4*)(yb + ((size_t)I * H_TOKN + J) * YSTR + q);
  }

  const bool valid = tid < 250;
  const int dh = tid / 10;
  const int dwb = (tid - dh * 10) * 10;
  const int hh = hr0 + dh;
  float th = fminf(fmaxf((hh + 0.5f) * SCALE - 0.5f, 0.f), 56.f);
  int i0 = min((int)th, 55);
  const float fh = th - (float)i0;
  const int ri = i0 - ib;
  const int* lrow = labels + ((size_t)b * OUT_HW + hh) * OUT_HW;

  f32x4 acc0 = {0.f,0.f,0.f,0.f}, acc1 = {0.f,0.f,0.f,0.f};
  int prevm = 0;
  const unsigned short one = 0x3F80;

  // register tap cache: u0/u1 = vertically-lerped tap columns curj, curj+1
  float u0[24], u1[24];
  int curj = -1000;
  #define LOADU(U, rj) { \
    const float* ta = &ytile[(ri * COLS_T + (rj)) * YTSTR]; \
    const float* tc = ta + COLS_T * YTSTR; \
    _Pragma("unroll") \
    for (int q = 0; q < 6; ++q) { \
      float4 A = *(const float4*)(ta + 4 * q); \
      float4 C = *(const float4*)(tc + 4 * q); \
      U[4*q+0] = A.x + fh * (C.x - A.x); \
      U[4*q+1] = A.y + fh * (C.y - A.y); \
      U[4*q+2] = A.z + fh * (C.z - A.z); \
      U[4*q+3] = A.w + fh * (C.w - A.w); } }

  __syncthreads();
  if (valid) zT[24 * ZPAD + tid] = one;         // ones-channel -> cnt

  for (int c = 0; c < 10; ++c) {
    if (valid) {
      int ww = wc0 + dwb + c;
      float tw = fminf(fmaxf((ww + 0.5f) * SCALE - 0.5f, 0.f), 56.f);
      int j0 = min((int)tw, 55);
      float fw = tw - (float)j0;
      int rj = j0 - jb;
      if (rj != curj) {
        if (rj == curj + 1) {
          #pragma unroll
          for (int ch = 0; ch < 24; ++ch) u0[ch] = u1[ch];
        } else {
          LOADU(u0, rj)
        }
        LOADU(u1, rj + 1)
        curj = rj;
      }
      int m = lrow[ww] & (NMASK - 1);
      #pragma unroll
      for (int ch = 0; ch < 24; ++ch)
        zT[ch * ZPAD + tid] = f2bf(u0[ch] + fw * (u1[ch] - u0[ch]));
      It[prevm * IPAD + tid] = 0;
      It[m * IPAD + tid] = one;
      prevm = m;
    }
    __syncthreads();
    #pragma unroll
    for (int ks = 0; ks < 8; ++ks) {
      bf16x8 a  = *(bf16x8*)&It[(wv * 16 + l15) * IPAD + ks * 32 + khi];
      bf16x8 b0 = *(bf16x8*)&zT[l15 * ZPAD + ks * 32 + khi];
      bf16x8 b1 = *(bf16x8*)&zT[(16 + l15) * ZPAD + ks * 32 + khi];
      acc0 = __builtin_amdgcn_mfma_f32_16x16x32_bf16(a, b0, acc0, 0, 0, 0);
      acc1 = __builtin_amdgcn_mfma_f32_16x16x32_bf16(a, b1, acc1, 0, 0, 0);
    }
    __syncthreads();
  }
  #undef LOADU

  float* pb = part + ((size_t)b * NSLICE +
                      (size_t)(blockIdx.y * gridDim.x + blockIdx.x)) * (NMASK * PSTR);
  const int g4 = (lane >> 4) << 2;
  #pragma unroll
  for (int r = 0; r < 4; ++r) {
    int m = wv * 16 + g4 + r;
    pb[m * PSTR + l15] = acc0[r];
    if (l15 <= 8) pb[m * PSTR + 16 + l15] = acc1[r];
  }
}

// ---------- Kernel B2: meanFg[b][m][28] = sum(part)/cnt + b2 (pads 0) ----------
__global__ __launch_bounds__(256) void reduce_kernel(
    const float* __restrict__ part, const float* __restrict__ b2,
    float* __restrict__ meanFg)
{
  const int bm = blockIdx.x;          // b*64 + m
  const int b = bm >> 6, m = bm & 63;
  const int tid = threadIdx.x;        // = slice
  const float* p = part + ((size_t)b * NSLICE + tid) * (NMASK * PSTR) + (size_t)m * PSTR;
  float4 v[7];
  #pragma unroll
  for (int q = 0; q < 7; ++q) v[q] = *(const float4*)(p + q * 4);
  #pragma unroll
  for (int off = 32; off > 0; off >>= 1) {
    #pragma unroll
    for (int q = 0; q < 7; ++q) {
      v[q].x += __shfl_down(v[q].x, off, 64);
      v[q].y += __shfl_down(v[q].y, off, 64);
      v[q].z += __shfl_down(v[q].z, off, 64);
      v[q].w += __shfl_down(v[q].w, off, 64);
    }
  }
  __shared__ float s_red[4][28];
  const int wid = tid >> 6, lane = tid & 63;
  if (lane == 0) {
    #pragma unroll
    for (int q = 0; q < 7; ++q) *(float4*)&s_red[wid][q * 4] = v[q];
  }
  __syncthreads();
  if (tid < 28) {
    float cnt = s_red[0][24] + s_red[1][24] + s_red[2][24] + s_red[3][24];
    float t = s_red[0][tid] + s_red[1][tid] + s_red[2][tid] + s_red[3][tid];
    float out = (tid < L_OUT) ? t / fmaxf(cnt, 1.f) + b2[tid] : 0.f;
    meanFg[(size_t)bm * MFSTR + tid] = out;
  }
}

// ---------- Kernel C: out[b][l][hh][w] = lerp_w(rowC)[l] + meanF[label][l] ----------
__global__ __launch_bounds__(256) void final_kernel(
    const float* __restrict__ y57, const int* __restrict__ labels,
    const float* __restrict__ meanFg, float* __restrict__ out)
{
  __shared__ __align__(16) float rowC[FROWS][H_TOKN * RCSTR];
  __shared__ __align__(16) float meanF[NMASK * MFSTR];
  const int tid = threadIdx.x;
  const int hh0 = blockIdx.y * FROWS;
  const int b = blockIdx.z;
  const float* yb = y57 + (size_t)b * NPIX * YSTR;

  for (int i = tid; i < FROWS * H_TOKN * 6; i += 256) {
    int r = i / (H_TOKN * 6);
    int rest = i - r * (H_TOKN * 6);
    int rr = rest / 6, q = (rest - rr * 6) * 4;
    float th = fminf(fmaxf((hh0 + r + 0.5f) * SCALE - 0.5f, 0.f), 56.f);
    int i0 = min((int)th, 55);
    float fh = th - (float)i0;
    const float* s0 = yb + ((size_t)i0 * H_TOKN + rr) * YSTR + q;
    float4 A = *(const float4*)s0;
    float4 B = *(const float4*)(s0 + H_TOKN * YSTR);
    *(float4*)&rowC[r][rr * RCSTR + q] = make_float4(
        A.x + fh * (B.x - A.x), A.y + fh * (B.y - A.y),
        A.z + fh * (B.z - A.z), A.w + fh * (B.w - A.w));
  }
  {
    const float* src = meanFg + (size_t)b * NMASK * MFSTR;
    for (int i = tid; i < NMASK * MFSTR / 4; i += 256)
      *(float4*)&meanF[i * 4] = *(const float4*)(src + i * 4);
  }
  __syncthreads();

  for (int g = tid; g < FROWS * 200; g += 256) {
    const int row = g / 200;
    const int gg = g - row * 200;
    const int w0 = gg * 4;
    const int hh = hh0 + row;
    const int* lrow = labels + ((size_t)b * OUT_HW + hh) * OUT_HW;
    int4 la = *(const int4*)(lrow + w0);
    float* ob = out + (size_t)b * L_OUT * OUT_HW * OUT_HW + (size_t)hh * OUT_HW + w0;
    const float* rc = rowC[row];

    float fwv[4]; const float* c0p[4]; const float* mfp[4];
    {
      int lam[4] = {la.x & 63, la.y & 63, la.z & 63, la.w & 63};
      #pragma unroll
      for (int k = 0; k < 4; ++k) {
        float tw = fminf(fmaxf((w0 + k + 0.5f) * SCALE - 0.5f, 0.f), 56.f);
        int j0 = min((int)tw, 55);
        fwv[k] = tw - (float)j0;
        c0p[k] = &rc[j0 * RCSTR];
        mfp[k] = &meanF[lam[k] * MFSTR];
      }
    }
    #pragma unroll
    for (int q = 0; q < 6; ++q) {
      float4 V[4];
      #pragma unroll
      for (int k = 0; k < 4; ++k) {
        float4 A  = *(const float4*)(c0p[k] + 4 * q);
        float4 Bv = *(const float4*)(c0p[k] + RCSTR + 4 * q);
        float4 Mv = *(const float4*)(mfp[k] + 4 * q);
        V[k].x = A.x + fwv[k] * (Bv.x - A.x) + Mv.x;
        V[k].y = A.y + fwv[k] * (Bv.y - A.y) + Mv.y;
        V[k].z = A.z + fwv[k] * (Bv.z - A.z) + Mv.z;
        V[k].w = A.w + fwv[k] * (Bv.w - A.w) + Mv.w;
      }
      const int l = 4 * q;
      *(float4*)(ob + (size_t)l * 640000) = make_float4(V[0].x, V[1].x, V[2].x, V[3].x);
      if (l + 1 < L_OUT)
        *(float4*)(ob + (size_t)(l+1) * 640000) = make_float4(V[0].y, V[1].y, V[2].y, V[3].y);
      if (l + 2 < L_OUT)
        *(float4*)(ob + (size_t)(l+2) * 640000) = make_float4(V[0].z, V[1].z, V[2].z, V[3].z);
      if (l + 3 < L_OUT)
        *(float4*)(ob + (size_t)(l+3) * 640000) = make_float4(V[0].w, V[1].w, V[2].w, V[3].w);
    }
  }
}

extern "C" void kernel_launch(void* const* d_in, const int* in_sizes, int n_in,
                              void* d_out, int out_size, void* d_ws, size_t ws_size,
                              hipStream_t stream)
{
  const float* e   = (const float*)d_in[0];
  const int*   lab = (const int*)d_in[1];
  const float* w1  = (const float*)d_in[2];
  const float* b1  = (const float*)d_in[3];
  const float* w2  = (const float*)d_in[4];
  const float* b2  = (const float*)d_in[5];
  float* out = (float*)d_out;
  float* ws  = (float*)d_ws;

  float* y57_ws = ws;                                     // 6498*24 f32
  float* part   = y57_ws + (size_t)M_TOT * YSTR;          // 2*256*64*28 f32
  float* meanFg = part + (size_t)2 * NSLICE * NMASK * PSTR; // 2*64*28 f32

  fused_conv_kernel<<<dim3((M_TOT + BM - 1) / BM), 256, 0, stream>>>(
      e, w1, b1, w2, y57_ws);
  binsum_kernel<<<dim3(OUT_HW / TILE_W, OUT_HW / TILE_H, 2), 256, 0, stream>>>(
      lab, y57_ws, part);
  reduce_kernel<<<dim3(2 * NMASK), 256, 0, stream>>>(part, b2, meanFg);
  final_kernel<<<dim3(1, OUT_HW / FROWS, 2), 256, 0, stream>>>(
      y57_ws, lab, meanFg, out);
}